// Round 2
// 231.117 us; speedup vs baseline: 1.0025x; 1.0025x over previous
//
#include <hip/hip_runtime.h>

#define B_TOTAL 16384
#define F 39
#define E 64
#define U 128
#define BT 64
#define THREADS 1024     // 16 waves: 8 u-col groups x 2 k-halves (split-K)

typedef __attribute__((ext_vector_type(8))) short short8;   // 8 bf16
typedef __attribute__((ext_vector_type(4))) float f32x4;
typedef __attribute__((ext_vector_type(4))) unsigned u32x4;

// pack two f32 -> packed bf16 pair (round-half-up)
__device__ __forceinline__ unsigned pack2_bf16(float a, float b) {
  unsigned ua = __builtin_bit_cast(unsigned, a) + 0x8000u;
  unsigned ub = __builtin_bit_cast(unsigned, b) + 0x8000u;
  return (ub & 0xFFFF0000u) | (ua >> 16);
}

// ---- prep: W (U,E,E) f32 -> SYMMETRIC-FOLDED fragment-ordered bf16 ----
// Quadratic form: lp = f^T W f = f^T S f with triangular fold at 32-granularity:
//   Shat[i<32 ][k<32 ] = (W[i,k]+W[k,i])/2      (diag block, halved)
//   Shat[i<32 ][k>=32] =  W[i,k]+W[k,i]         (cross block, folded x2)
//   Shat[i>=32][k>=32] = (W[i,k]+W[k,i])/2      (diag block, halved)
//   Shat[i>=32][k<32 ] = 0                       (never read; MFMA skipped)
// wf[(i*8+ntg)*2+ks][lane] = bf16(Shat[ntg*16+(lane&15)][i][ks*32+(lane>>4)*8..+7])
__global__ __launch_bounds__(256) void prep_w(const float* __restrict__ w,
                                              u32x4* __restrict__ wf) {
  int tid = blockIdx.x * 256 + threadIdx.x;   // 65536 = 1024 frags * 64 lanes
  int lane = tid & 63;
  int frag = tid >> 6;
  int ks  = frag & 1;
  int ntg = (frag >> 1) & 7;
  int i   = frag >> 4;
  int uu  = ntg * 16 + (lane & 15);
  int k0  = ks * 32 + (lane >> 4) * 8;
  int ihi = i >> 5;                 // i >= 32 ?  (wave-uniform: frag is)
  if (ihi && !ks) {                 // dead lower-left quarter: zero, never read
    wf[tid] = (u32x4){0u, 0u, 0u, 0u};
    return;
  }
  float c = (ihi == ks) ? 0.5f : 1.0f;
  const float* rowp = w + (size_t)uu * (E * E) + i * E + k0;   // W[uu,i,k0+j]
  const float* colp = w + (size_t)uu * (E * E) + (size_t)k0 * E + i; // W[uu,k0+j,i]
  // plain (cached) loads: W is 2 MiB, row+col patterns share lines via L2
  f32x4 v0 = *(const f32x4*)rowp;
  f32x4 v1 = *(const f32x4*)(rowp + 4);
  float col[8];
  #pragma unroll
  for (int j = 0; j < 8; ++j) col[j] = colp[(size_t)j * E];
  u32x4 o;
  o[0] = pack2_bf16(c * (v0[0] + col[0]), c * (v0[1] + col[1]));
  o[1] = pack2_bf16(c * (v0[2] + col[2]), c * (v0[3] + col[3]));
  o[2] = pack2_bf16(c * (v1[0] + col[4]), c * (v1[1] + col[5]));
  o[3] = pack2_bf16(c * (v1[2] + col[6]), c * (v1[3] + col[7]));
  wf[tid] = o;   // normal store: wf should be L2-resident for fused_outer
}

// ---- fused: feat_sum (phase 1) + quadratic form via MFMA, split-K ----
// grid 256 x 1024. Wave (uc, kh): uc owns u-cols [uc*16,uc*16+16).
// kh=0 owns i in [0,32) with BOTH k-halves (2 MFMA per (i,mt));
// kh=1 owns i in [32,64) with k-half 1 ONLY (1 MFMA per (i,mt)) -- the
// triangular fold. 3072 MFMA/block (was 4096); W frags 0.75 MiB/block.
// Per-SIMD balance: waves 0-7 (kh=0, heavy) and 8-15 (kh=1, light) land
// 2+2 on each SIMD.
__global__ __launch_bounds__(THREADS) void fused_outer(
    const float* __restrict__ embeds, const u32x4* __restrict__ wf,
    float* __restrict__ out) {
  // smem0 aliases: Ft [64][68] f32 (phase1 .. af-build), then split-K partials
  // [8 uc][64 lane][4 mt] f32x4 (after K-loop). Barrier2 separates lifetimes.
  __shared__ __align__(16) char smem0[32768];
  __shared__ __align__(16) float FtT[E * 68];   // [e][b], live whole kernel
  float* Ft  = (float*)smem0;
  f32x4* prt = (f32x4*)smem0;

  const int t = threadIdx.x;
  const int b0 = blockIdx.x * BT;

  // ---------------- Phase 1: feat_sum over F (one task per thread) --------
  // NT loads: embeds streamed once; don't allocate into poisoned L2/L3.
  {
    const int b = t >> 4, e4 = t & 15;
    const f32x4* src = (const f32x4*)(embeds + (size_t)(b0 + b) * (F * E)) + e4;
    f32x4 s = {0.f, 0.f, 0.f, 0.f};
    #pragma unroll
    for (int f = 0; f < F; ++f)
      s += __builtin_nontemporal_load(src + f * (E / 4));
    *(f32x4*)&Ft[b * 68 + e4 * 4] = s;
    FtT[(e4 * 4 + 0) * 68 + b] = s[0];
    FtT[(e4 * 4 + 1) * 68 + b] = s[1];
    FtT[(e4 * 4 + 2) * 68 + b] = s[2];
    FtT[(e4 * 4 + 3) * 68 + b] = s[3];
  }

  const int lane = t & 63, wave = t >> 6;
  const int uc = wave & 7;           // u-col group: cols [uc*16, uc*16+16)
  const int kh = wave >> 3;          // i-half: [kh*32, kh*32+32)
  const int fl = lane & 15;          // A row / C col index
  const int fo = (lane >> 4) * 8;    // k-octet
  const int r0 = (lane >> 4) * 4;    // C row base

  // frag index for (i, ks) = i*16 + uc*2 + ks; lane-resolved bases:
  const u32x4* wv  = wf + (size_t)(uc * 2) * 64 + lane;       // ks=0 base
  const u32x4* wv1 = wf + (size_t)(uc * 2 + 1) * 64 + lane;   // ks=1 base

  #define LOADW(buf, ii) {                 \
    buf[0] = wv[(size_t)((ii) * 16) * 64]; \
    buf[1] = wv[(size_t)((ii) * 16 + 1) * 64]; }
  #define LOADW1(dst, ii) { dst = wv1[(size_t)((ii) * 16) * 64]; }

  // depth-4 register pipeline; first 4 issued BEFORE the barrier.
  u32x4 w0[2], w1[2], w2[2], w3[2];
  if (kh == 0) {
    LOADW(w0, 0);
    LOADW(w1, 1);
    LOADW(w2, 2);
    LOADW(w3, 3);
  } else {
    LOADW1(w0[0], 32);
    LOADW1(w1[0], 33);
    LOADW1(w2[0], 34);
    LOADW1(w3[0], 35);
  }
  __syncthreads();   // barrier1: Ft/FtT ready

  // A-fragments (i-independent): af[mt][ks] = bf16(f[mt*16+fl][ks*32+fo..+7])
  short8 af[4][2];
  #pragma unroll
  for (int mt = 0; mt < 4; ++mt) {
    const float* fr = &Ft[(mt * 16 + fl) * 68];
    #pragma unroll
    for (int ks = 0; ks < 2; ++ks) {
      f32x4 v0 = *(const f32x4*)&fr[ks * 32 + fo];
      f32x4 v1 = *(const f32x4*)&fr[ks * 32 + fo + 4];
      u32x4 o;
      o[0] = pack2_bf16(v0[0], v0[1]);
      o[1] = pack2_bf16(v0[2], v0[3]);
      o[2] = pack2_bf16(v1[0], v1[1]);
      o[3] = pack2_bf16(v1[2], v1[3]);
      af[mt][ks] = __builtin_bit_cast(short8, o);
    }
  }
  __syncthreads();   // barrier2: all Ft reads done; smem0 becomes 'prt'

  f32x4 acc[4];
  #pragma unroll
  for (int mt = 0; mt < 4; ++mt)
    #pragma unroll
    for (int r = 0; r < 4; ++r) acc[mt][r] = 0.f;

  // kh=0: 2 MFMA per (i,mt) over both k-halves
  #define STEP(ii, buf) {                                                      \
    short8 bf0 = __builtin_bit_cast(short8, buf[0]);                           \
    short8 bf1 = __builtin_bit_cast(short8, buf[1]);                           \
    _Pragma("unroll")                                                          \
    for (int mt = 0; mt < 4; ++mt) {                                           \
      f32x4 s = {0.f, 0.f, 0.f, 0.f};                                          \
      s = __builtin_amdgcn_mfma_f32_16x16x32_bf16(af[mt][0], bf0, s, 0, 0, 0); \
      s = __builtin_amdgcn_mfma_f32_16x16x32_bf16(af[mt][1], bf1, s, 0, 0, 0); \
      f32x4 fi = *(const f32x4*)&FtT[(ii) * 68 + mt * 16 + r0];                \
      acc[mt] += fi * s;                                                       \
    } }

  // kh=1: 1 MFMA per (i,mt), k-half 1 only (triangular fold)
  #define STEP1(ii, buf) {                                                     \
    short8 bf1 = __builtin_bit_cast(short8, buf);                              \
    _Pragma("unroll")                                                          \
    for (int mt = 0; mt < 4; ++mt) {                                           \
      f32x4 s = {0.f, 0.f, 0.f, 0.f};                                          \
      s = __builtin_amdgcn_mfma_f32_16x16x32_bf16(af[mt][1], bf1, s, 0, 0, 0); \
      f32x4 fi = *(const f32x4*)&FtT[(ii) * 68 + mt * 16 + r0];                \
      acc[mt] += fi * s;                                                       \
    } }

  // K-loop: no barriers. Tail prefetches read dead ws past wf (<1.1 MiB into
  // ws; unused, legal).
  if (kh == 0) {
    for (int i = 0; i < 32; i += 4) {
      STEP(i, w0);     LOADW(w0, i + 4);
      STEP(i + 1, w1); LOADW(w1, i + 5);
      STEP(i + 2, w2); LOADW(w2, i + 6);
      STEP(i + 3, w3); LOADW(w3, i + 7);
    }
  } else {
    for (int i = 32; i < 64; i += 4) {
      STEP1(i, w0[0]);     LOADW1(w0[0], i + 4);
      STEP1(i + 1, w1[0]); LOADW1(w1[0], i + 5);
      STEP1(i + 2, w2[0]); LOADW1(w2[0], i + 6);
      STEP1(i + 3, w3[0]); LOADW1(w3[0], i + 7);
    }
  }

  // ---------------- split-K combine + epilogue ----------------
  if (kh == 1) {
    #pragma unroll
    for (int mt = 0; mt < 4; ++mt)
      prt[(uc * 64 + lane) * 4 + mt] = acc[mt];
  }
  __syncthreads();   // barrier3
  if (kh == 0) {
    // C/D layout col=lane&15 (u), row=(lane>>4)*4+r (b)
    #pragma unroll
    for (int mt = 0; mt < 4; ++mt) {
      f32x4 v = acc[mt] + prt[(uc * 64 + lane) * 4 + mt];
      #pragma unroll
      for (int r = 0; r < 4; ++r)
        __builtin_nontemporal_store(
            v[r], &out[(size_t)(b0 + mt * 16 + r0 + r) * U + uc * 16 + fl]);
    }
  }
  #undef LOADW
  #undef LOADW1
  #undef STEP
  #undef STEP1
}

extern "C" void kernel_launch(void* const* d_in, const int* in_sizes, int n_in,
                              void* d_out, int out_size, void* d_ws, size_t ws_size,
                              hipStream_t stream) {
  const float* embeds = (const float*)d_in[0];
  const float* w      = (const float*)d_in[1];
  float* out          = (float*)d_out;
  u32x4* wf           = (u32x4*)d_ws;   // 1 MiB used (+ dead-read slack)
  prep_w<<<dim3(256), dim3(256), 0, stream>>>(w, wf);
  fused_outer<<<dim3(B_TOTAL / BT), dim3(THREADS), 0, stream>>>(embeds, wf, out);
}